// Round 3
// baseline (9221.441 us; speedup 1.0000x reference)
//
#include <hip/hip_runtime.h>
#include <stdint.h>

#define NN    100000
#define EE    400000
#define NNZK  800000
#define ADJK  400000
#define DDIM  100
#define DOUTK 300
#define RT    16

typedef unsigned short u16;
typedef unsigned int   u32;

__device__ __forceinline__ float bf2f(u16 b) { return __uint_as_float(((u32)b) << 16); }
__device__ __forceinline__ u16 f2bf(float x) {
    u32 u = __float_as_uint(x);
    u32 r = (u + 0x7FFFu + ((u >> 16) & 1u)) >> 16;  // RNE
    return (u16)r;
}

// ---- rels_sum scatter: scratch[e] += val[i] * emb[k]  (half-edge-range filtered) ----
__global__ __launch_bounds__(256) void rels_scatter(
    const int* __restrict__ sp, const float* __restrict__ val, const float* __restrict__ emb,
    float* __restrict__ scratch, int eLo, int eHi, int kMax, int nnz)
{
    int t = blockIdx.x * 256 + threadIdx.x;
    if (t >= nnz * 25) return;
    int i = t / 25, c = (t - i * 25) * 4;
    int e = sp[2 * i];
    if (e < eLo || e >= eHi) return;
    int k = sp[2 * i + 1];
    if (k < 0 || k >= kMax) return;          // guard (diagnostic safety)
    float v = val[i];
    float4 ev = *(const float4*)(emb + (size_t)k * DDIM + c);
    float* dst = scratch + (size_t)(e - eLo) * DDIM + c;
    atomicAdd(dst + 0, v * ev.x);
    atomicAdd(dst + 1, v * ev.y);
    atomicAdd(dst + 2, v * ev.z);
    atomicAdd(dst + 3, v * ev.w);
}

// ---- l2-normalize rels rows, fp32 scratch -> packed bf16 ----
__global__ __launch_bounds__(256) void rels_normalize(
    const float* __restrict__ scratch, u16* __restrict__ out, int eLo, int nE)
{
    int w = blockIdx.x * 4 + (threadIdx.x >> 6);
    int lane = threadIdx.x & 63;
    if (w >= nE) return;
    const float* src = scratch + (size_t)w * DDIM;
    float v1 = src[lane];
    int d2 = lane + 64;
    float v2 = (d2 < DDIM) ? src[d2] : 0.f;
    float s = v1 * v1 + v2 * v2;
#pragma unroll
    for (int m = 32; m; m >>= 1) s += __shfl_xor(s, m, 64);
    float sc = 1.f / fmaxf(sqrtf(s), 1e-12f);
    u16* o = out + (size_t)(eLo + w) * DDIM;
    o[lane] = f2bf(v1 * sc);
    if (d2 < DDIM) o[d2] = f2bf(v2 * sc);
}

// ---- per-row counts ----
__global__ __launch_bounds__(256) void count_kernel(
    const int* __restrict__ idx, float* __restrict__ cnt, int nnz)
{
    int t = blockIdx.x * 256 + threadIdx.x;
    if (t >= nnz) return;
    int row = idx[2 * t];
    if (row < 0 || row >= NN) return;        // guard
    atomicAdd(&cnt[row], 1.0f);
}

// ---- feature mean-aggregation scatter: dst[row] += emb[col]/cnt[row] ----
__global__ __launch_bounds__(256) void feat_scatter(
    const int* __restrict__ idx, const float* __restrict__ emb, const float* __restrict__ cnt,
    float* __restrict__ dst, int colMax, int nnz)
{
    int t = blockIdx.x * 256 + threadIdx.x;
    if (t >= nnz * 25) return;
    int i = t / 25, c = (t - i * 25) * 4;
    int row = idx[2 * i], col = idx[2 * i + 1];
    if (row < 0 || row >= NN || col < 0 || col >= colMax) return;   // guard
    float inv = 1.0f / cnt[row];
    float4 ev = *(const float4*)(emb + (size_t)col * DDIM + c);
    float* d = dst + (size_t)row * DOUTK + c;
    atomicAdd(d + 0, inv * ev.x);
    atomicAdd(d + 1, inv * ev.y);
    atomicAdd(d + 2, inv * ev.z);
    atomicAdd(d + 3, inv * ev.w);
}

// ---- tanh over one 100-wide column block of the N x 300 buffer ----
__global__ __launch_bounds__(256) void tanh_block(
    float* __restrict__ buf, int colBase, int total)
{
    int t = blockIdx.x * 256 + threadIdx.x;
    if (t >= total) return;
    int n = t / DDIM, d = t - n * DDIM;
    float* p = buf + (size_t)n * DOUTK + colBase + d;
    *p = tanhf(*p);
}

// ---- attention: exp(dot(rels, attn[l])) + per-row denominators, both layers ----
__global__ __launch_bounds__(256) void att_exp(
    const int* __restrict__ adj, const u16* __restrict__ rels, const float* __restrict__ attn,
    float* __restrict__ att0, float* __restrict__ att1,
    float* __restrict__ den0, float* __restrict__ den1, int nE)
{
    int w = blockIdx.x * 4 + (threadIdx.x >> 6);
    int lane = threadIdx.x & 63;
    if (w >= nE) return;
    const u16* r = rels + (size_t)w * DDIM;
    float r1 = bf2f(r[lane]);
    int d2 = lane + 64;
    float r2 = (d2 < DDIM) ? bf2f(r[d2]) : 0.f;
    float a0 = attn[lane];
    float a0b = (d2 < DDIM) ? attn[d2] : 0.f;
    float a1 = attn[DDIM + lane];
    float a1b = (d2 < DDIM) ? attn[DDIM + d2] : 0.f;
    float p0 = r1 * a0 + r2 * a0b;
    float p1 = r1 * a1 + r2 * a1b;
#pragma unroll
    for (int m = 32; m; m >>= 1) { p0 += __shfl_xor(p0, m, 64); p1 += __shfl_xor(p1, m, 64); }
    if (lane == 0) {
        float e0 = expf(p0), e1 = expf(p1);
        att0[w] = e0; att1[w] = e1;
        int row = adj[2 * w];
        if (row >= 0 && row < NN) {          // guard
            atomicAdd(&den0[row], e0);
            atomicAdd(&den1[row], e1);
        }
    }
}

__global__ __launch_bounds__(256) void att_norm(
    const int* __restrict__ adj, float* __restrict__ att0, float* __restrict__ att1,
    const float* __restrict__ den0, const float* __restrict__ den1, int nE)
{
    int t = blockIdx.x * 256 + threadIdx.x;
    if (t >= nE) return;
    int row = adj[2 * t];
    if (row < 0 || row >= NN) { att0[t] = 0.f; att1[t] = 0.f; return; }   // guard
    att0[t] /= den0[row];
    att1[t] /= den1[row];
}

// ---- one message-passing layer: dst[row] += att*(f[col] - 2*dot(f[col],rels)*rels) ----
__global__ __launch_bounds__(256) void edge_layer(
    const int* __restrict__ adj, const u16* __restrict__ rels, const float* __restrict__ att,
    const float* __restrict__ src, float* __restrict__ dst, int nE)
{
    int w = blockIdx.x * 4 + (threadIdx.x >> 6);
    int lane = threadIdx.x & 63;
    if (w >= nE) return;
    int row = adj[2 * w], col = adj[2 * w + 1];
    if (row < 0 || row >= NN || col < 0 || col >= NN) return;   // guard
    const u16* r = rels + (size_t)w * DDIM;
    const float* f = src + (size_t)col * DOUTK;
    float r1 = bf2f(r[lane]), f1 = f[lane];
    int d2 = lane + 64;
    float r2 = 0.f, f2 = 0.f;
    if (d2 < DDIM) { r2 = bf2f(r[d2]); f2 = f[d2]; }
    float p = f1 * r1 + f2 * r2;
#pragma unroll
    for (int m = 32; m; m >>= 1) p += __shfl_xor(p, m, 64);
    float a = att[w];
    float* o = dst + (size_t)row * DOUTK;
    atomicAdd(&o[lane], a * (f1 - 2.f * p * r1));
    if (d2 < DDIM) atomicAdd(&o[d2], a * (f2 - 2.f * p * r2));
}

// ---- inverse norms of proxy rows ----
__global__ __launch_bounds__(64) void proxy_norms(const float* __restrict__ proxy, float* __restrict__ pn)
{
    int k = threadIdx.x;
    if (k >= 64) return;
    float s = 0.f;
    for (int i = 0; i < DOUTK; ++i) { float v = proxy[k * DOUTK + i]; s += v * v; }
    pn[k] = 1.f / fmaxf(sqrtf(s), 1e-12f);
}

// ---- fused epilogue: l2norm -> proxy softmax -> pf -> gate GEMM -> gated mix -> fp32 out ----
__global__ __launch_bounds__(256) void epilogue(
    const float* __restrict__ outbuf, const float* __restrict__ proxy, const float* __restrict__ pn,
    const float* __restrict__ gate_k, const float* __restrict__ bias,
    float* __restrict__ dout, float alpha, int accumulate)
{
    __shared__ __align__(16) float s_out[RT][DOUTK];
    __shared__ __align__(16) float s_pf[RT][DOUTK];
    __shared__ float s_pa[RT][64];
    __shared__ float s_rn[RT];
    __shared__ float s_pinv[RT];
    int tid = threadIdx.x;
    size_t rowBase = (size_t)blockIdx.x * RT;

    for (int x = tid; x < RT * DOUTK; x += 256) {
        int r = x / DOUTK, i = x - r * DOUTK;
        s_out[r][i] = outbuf[(rowBase + r) * DOUTK + i];
    }
    __syncthreads();

    { // row inverse norms (16 lanes per row)
        int r = tid >> 4, l16 = tid & 15;
        float s = 0.f;
        for (int i = l16; i < DOUTK; i += 16) { float v = s_out[r][i]; s += v * v; }
#pragma unroll
        for (int m = 8; m; m >>= 1) s += __shfl_xor(s, m, 64);
        if (l16 == 0) s_rn[r] = 1.f / fmaxf(sqrtf(s), 1e-12f);
    }
    __syncthreads();

    { // pa logits -> exp (thread = (proxy k, row-group)); each handles 4 rows
        int k = tid & 63, rg = tid >> 6;
        float acc0 = 0.f, acc1 = 0.f, acc2 = 0.f, acc3 = 0.f;
        const float* pk = proxy + k * DOUTK;
        for (int i = 0; i < DOUTK; i += 2) {
            float pA = pk[i], pB = pk[i + 1];
            acc0 += s_out[rg][i] * pA + s_out[rg][i + 1] * pB;
            acc1 += s_out[rg + 4][i] * pA + s_out[rg + 4][i + 1] * pB;
            acc2 += s_out[rg + 8][i] * pA + s_out[rg + 8][i + 1] * pB;
            acc3 += s_out[rg + 12][i] * pA + s_out[rg + 12][i + 1] * pB;
        }
        float pnk = pn[k];
        s_pa[rg][k]      = expf(acc0 * s_rn[rg] * pnk);
        s_pa[rg + 4][k]  = expf(acc1 * s_rn[rg + 4] * pnk);
        s_pa[rg + 8][k]  = expf(acc2 * s_rn[rg + 8] * pnk);
        s_pa[rg + 12][k] = expf(acc3 * s_rn[rg + 12] * pnk);
    }
    __syncthreads();

    { // softmax denominators
        int r = tid >> 4, l16 = tid & 15;
        float s = s_pa[r][l16] + s_pa[r][l16 + 16] + s_pa[r][l16 + 32] + s_pa[r][l16 + 48];
#pragma unroll
        for (int m = 8; m; m >>= 1) s += __shfl_xor(s, m, 64);
        if (l16 == 0) s_pinv[r] = 1.f / s;
    }
    __syncthreads();

    { // pf = out - (pa @ proxy)   (thread = column)
        int j = tid, j2 = tid + 256;
        float acc[RT], accB[RT];
#pragma unroll
        for (int r = 0; r < RT; ++r) { acc[r] = 0.f; accB[r] = 0.f; }
        for (int k = 0; k < 64; ++k) {
            float p1 = proxy[k * DOUTK + j];
            float p2 = (j2 < DOUTK) ? proxy[k * DOUTK + j2] : 0.f;
#pragma unroll
            for (int r = 0; r < RT; ++r) {
                float wgt = s_pa[r][k];
                acc[r] += wgt * p1;
                accB[r] += wgt * p2;
            }
        }
#pragma unroll
        for (int r = 0; r < RT; ++r) {
            s_pf[r][j] = s_out[r][j] - acc[r] * s_pinv[r];
            if (j2 < DOUTK) s_pf[r][j2] = s_out[r][j2] - accB[r] * s_pinv[r];
        }
    }
    __syncthreads();

    { // gate GEMM + gated mix + fp32 store
        int j = tid, j2 = tid + 256;
        float z[RT], z2[RT];
#pragma unroll
        for (int r = 0; r < RT; ++r) { z[r] = 0.f; z2[r] = 0.f; }
        for (int i0 = 0; i0 < DOUTK; i0 += 4) {
            float g0 = gate_k[(i0 + 0) * DOUTK + j];
            float g1 = gate_k[(i0 + 1) * DOUTK + j];
            float g2 = gate_k[(i0 + 2) * DOUTK + j];
            float g3 = gate_k[(i0 + 3) * DOUTK + j];
            float h0 = 0.f, h1 = 0.f, h2 = 0.f, h3 = 0.f;
            if (j2 < DOUTK) {
                h0 = gate_k[(i0 + 0) * DOUTK + j2];
                h1 = gate_k[(i0 + 1) * DOUTK + j2];
                h2 = gate_k[(i0 + 2) * DOUTK + j2];
                h3 = gate_k[(i0 + 3) * DOUTK + j2];
            }
#pragma unroll
            for (int r = 0; r < RT; ++r) {
                float4 p = *(const float4*)&s_pf[r][i0];
                z[r]  += p.x * g0 + p.y * g1 + p.z * g2 + p.w * g3;
                z2[r] += p.x * h0 + p.y * h1 + p.z * h2 + p.w * h3;
            }
        }
        float b1 = bias[j];
        float b2 = (j2 < DOUTK) ? bias[j2] : 0.f;
#pragma unroll
        for (int r = 0; r < RT; ++r) {
            size_t row = rowBase + r;
            {
                float g = 1.f / (1.f + expf(-(z[r] + b1)));
                float res = (g * s_out[r][j] + (1.f - g) * s_pf[r][j]) * alpha;
                float* o = dout + row * 600 + j;
                if (accumulate) res += *o;
                *o = res;
            }
            if (j2 < DOUTK) {
                float g = 1.f / (1.f + expf(-(z2[r] + b2)));
                float res = (g * s_out[r][j2] + (1.f - g) * s_pf[r][j2]) * alpha;
                float* o = dout + row * 600 + j2;
                if (accumulate) res += *o;
                *o = res;
            }
        }
    }
}

extern "C" void kernel_launch(void* const* d_in, const int* in_sizes, int n_in,
                              void* d_out, int out_size, void* d_ws, size_t ws_size,
                              hipStream_t stream)
{
    const int*   adj      = (const int*)d_in[0];
    const int*   r_index  = (const int*)d_in[1];
    const float* r_val    = (const float*)d_in[2];
    const int*   t_index  = (const int*)d_in[3];
    const int*   ent_adj  = (const int*)d_in[4];
    const int*   rel_adj  = (const int*)d_in[5];
    const int*   time_adj = (const int*)d_in[6];
    const float* ent_emb  = (const float*)d_in[7];
    const float* rel_emb  = (const float*)d_in[8];
    const float* time_emb = (const float*)d_in[9];
    const float* e_attn   = (const float*)d_in[10];
    const float* e_gate   = (const float*)d_in[11];
    const float* e_proxy  = (const float*)d_in[12];
    const float* e_bias   = (const float*)d_in[13];
    const float* r_attn   = (const float*)d_in[14];
    const float* r_gate   = (const float*)d_in[15];
    const float* r_proxy  = (const float*)d_in[16];
    const float* r_bias   = (const float*)d_in[17];
    float* out = (float*)d_out;

    // ---- compact workspace layout: ~205 MB total ----
    char* ws = (char*)d_ws;
    size_t off = 0;
    auto alloc = [&](size_t bytes) { void* p = ws + off; off += (bytes + 255) & ~255ULL; return p; };
    u16* rels     = (u16*)alloc((size_t)EE * DDIM * 2);       // 80 MB (relsR for enc0+enc1, then relsT)
    float* outbuf = (float*)alloc((size_t)NN * DOUTK * 4);    // 120 MB (also rels fp32 scratch)
    float* att0   = (float*)alloc((size_t)EE * 4);
    float* att1   = (float*)alloc((size_t)EE * 4);
    float* den0   = (float*)alloc((size_t)NN * 4);
    float* den1   = (float*)alloc((size_t)NN * 4);
    float* cnt    = (float*)alloc((size_t)NN * 4);
    float* pnE    = (float*)alloc(64 * 4);
    float* pnR    = (float*)alloc(64 * 4);
    float* scratch = outbuf;  // time-shared: rels builds happen while outbuf is dead

    proxy_norms<<<1, 64, 0, stream>>>(e_proxy, pnE);
    proxy_norms<<<1, 64, 0, stream>>>(r_proxy, pnR);

    const int EHALF = EE / 2;
    const int sc_grid = (NNZK * 25 + 255) / 256;
    auto build_rels = [&](const int* sp, const float* emb, int kMax) {
        for (int h = 0; h < 2; ++h) {
            hipMemsetAsync(scratch, 0, (size_t)EHALF * DDIM * 4, stream);
            rels_scatter<<<sc_grid, 256, 0, stream>>>(sp, r_val, emb, scratch, h * EHALF, (h + 1) * EHALF, kMax, NNZK);
            rels_normalize<<<(EHALF + 3) / 4, 256, 0, stream>>>(scratch, rels, h * EHALF, EHALF);
        }
    };

    struct Enc {
        const int* fadj; const float* femb; int colMax; const float* attn;
        const float* gate; const float* proxy; const float* pn; const float* bias;
        int dcol; float alpha; int accum;
    };
    Enc encs[3] = {
        { ent_adj,  ent_emb,  NN,   e_attn, e_gate, e_proxy, pnE, e_bias,   0, 1.0f, 0 },
        { rel_adj,  rel_emb,  2000, r_attn, r_gate, r_proxy, pnR, r_bias, 300, 0.5f, 0 },
        { time_adj, time_emb, 1000, e_attn, e_gate, e_proxy, pnE, e_bias, 300, 0.5f, 1 },
    };

    const int fs_grid = (ADJK * 25 + 255) / 256;
    const int th_grid = (NN * DDIM + 255) / 256;
    const int ew_grid = (EE + 3) / 4;

    build_rels(r_index, rel_emb, 2000);     // relsR, used by enc 0 and 1
    for (int c = 0; c < 3; ++c) {
        if (c == 2) build_rels(t_index, time_emb, 1000);   // relsT replaces relsR (outbuf dead here)
        const Enc& e = encs[c];
        hipMemsetAsync(outbuf, 0, (size_t)NN * DOUTK * 4, stream);
        hipMemsetAsync(cnt, 0, (size_t)NN * 4, stream);
        count_kernel<<<(ADJK + 255) / 256, 256, 0, stream>>>(e.fadj, cnt, ADJK);
        feat_scatter<<<fs_grid, 256, 0, stream>>>(e.fadj, e.femb, cnt, outbuf, e.colMax, ADJK);
        tanh_block<<<th_grid, 256, 0, stream>>>(outbuf, 0, NN * DDIM);
        hipMemsetAsync(den0, 0, (size_t)NN * 4, stream);
        hipMemsetAsync(den1, 0, (size_t)NN * 4, stream);
        att_exp<<<ew_grid, 256, 0, stream>>>(adj, rels, e.attn, att0, att1, den0, den1, EE);
        att_norm<<<(EE + 255) / 256, 256, 0, stream>>>(adj, att0, att1, den0, den1, EE);
        edge_layer<<<ew_grid, 256, 0, stream>>>(adj, rels, att0, outbuf, outbuf + DDIM, EE);
        tanh_block<<<th_grid, 256, 0, stream>>>(outbuf, DDIM, NN * DDIM);
        edge_layer<<<ew_grid, 256, 0, stream>>>(adj, rels, att1, outbuf + DDIM, outbuf + 2 * DDIM, EE);
        tanh_block<<<th_grid, 256, 0, stream>>>(outbuf, 2 * DDIM, NN * DDIM);
        epilogue<<<NN / RT, 256, 0, stream>>>(outbuf, e.proxy, e.pn, e.gate, e.bias,
                                              out + e.dcol, e.alpha, e.accum);
    }
}

// Round 4
// 7339.924 us; speedup vs baseline: 1.2563x; 1.2563x over previous
//
#include <hip/hip_runtime.h>
#include <stdint.h>

#define NN    100000
#define EE    400000
#define NNZK  800000
#define ADJK  400000
#define DDIM  100
#define DOUTK 300

typedef unsigned short u16;
typedef unsigned int   u32;
typedef __attribute__((ext_vector_type(8))) short short8;
typedef __attribute__((ext_vector_type(4))) float f32x4;

__device__ __forceinline__ float bf2f(u16 b) { return __uint_as_float(((u32)b) << 16); }
__device__ __forceinline__ u16 f2bf(float x) {
    u32 u = __float_as_uint(x);
    u32 r = (u + 0x7FFFu + ((u >> 16) & 1u)) >> 16;  // RNE
    return (u16)r;
}
// pack fp32 -> (bf16_hi << 16) | bf16_lo, truncation split: hi+lo == x to ~2^-17 rel
__device__ __forceinline__ u32 pack_hl(float x) {
    u32 u = __float_as_uint(x);
    u32 h = u >> 16;
    float hf = __uint_as_float(h << 16);
    u32 l = __float_as_uint(x - hf) >> 16;
    return (h << 16) | (l & 0xFFFFu);
}
__device__ __forceinline__ float unpack_f32(u32 p) {
    return __uint_as_float(p & 0xFFFF0000u) + __uint_as_float(p << 16);
}
__device__ __forceinline__ void unpack_frag(const u32* __restrict__ src, short8& hi, short8& lo) {
#pragma unroll
    for (int j = 0; j < 8; ++j) {
        u32 u = src[j];
        hi[j] = (short)(u >> 16);
        lo[j] = (short)(u & 0xFFFFu);
    }
}

// ---- rels_sum scatter: scratch[e] += val[i] * emb[k]  (half-edge-range filtered) ----
__global__ __launch_bounds__(256) void rels_scatter(
    const int* __restrict__ sp, const float* __restrict__ val, const float* __restrict__ emb,
    float* __restrict__ scratch, int eLo, int eHi, int kMax, int nnz)
{
    int t = blockIdx.x * 256 + threadIdx.x;
    if (t >= nnz * 25) return;
    int i = t / 25, c = (t - i * 25) * 4;
    int e = sp[2 * i];
    if (e < eLo || e >= eHi) return;
    int k = sp[2 * i + 1];
    if (k < 0 || k >= kMax) return;
    float v = val[i];
    float4 ev = *(const float4*)(emb + (size_t)k * DDIM + c);
    float* dst = scratch + (size_t)(e - eLo) * DDIM + c;
    atomicAdd(dst + 0, v * ev.x);
    atomicAdd(dst + 1, v * ev.y);
    atomicAdd(dst + 2, v * ev.z);
    atomicAdd(dst + 3, v * ev.w);
}

// ---- l2-normalize rels rows, fp32 scratch -> packed bf16 ----
__global__ __launch_bounds__(256) void rels_normalize(
    const float* __restrict__ scratch, u16* __restrict__ out, int eLo, int nE)
{
    int w = blockIdx.x * 4 + (threadIdx.x >> 6);
    int lane = threadIdx.x & 63;
    if (w >= nE) return;
    const float* src = scratch + (size_t)w * DDIM;
    float v1 = src[lane];
    int d2 = lane + 64;
    float v2 = (d2 < DDIM) ? src[d2] : 0.f;
    float s = v1 * v1 + v2 * v2;
#pragma unroll
    for (int m = 32; m; m >>= 1) s += __shfl_xor(s, m, 64);
    float sc = 1.f / fmaxf(sqrtf(s), 1e-12f);
    u16* o = out + (size_t)(eLo + w) * DDIM;
    o[lane] = f2bf(v1 * sc);
    if (d2 < DDIM) o[d2] = f2bf(v2 * sc);
}

// ---- per-row counts ----
__global__ __launch_bounds__(256) void count_kernel(
    const int* __restrict__ idx, float* __restrict__ cnt, int nnz)
{
    int t = blockIdx.x * 256 + threadIdx.x;
    if (t >= nnz) return;
    int row = idx[2 * t];
    if (row < 0 || row >= NN) return;
    atomicAdd(&cnt[row], 1.0f);
}

// ---- feature mean-aggregation scatter: dst[row] += emb[col]/cnt[row] ----
__global__ __launch_bounds__(256) void feat_scatter(
    const int* __restrict__ idx, const float* __restrict__ emb, const float* __restrict__ cnt,
    float* __restrict__ dst, int colMax, int nnz)
{
    int t = blockIdx.x * 256 + threadIdx.x;
    if (t >= nnz * 25) return;
    int i = t / 25, c = (t - i * 25) * 4;
    int row = idx[2 * i], col = idx[2 * i + 1];
    if (row < 0 || row >= NN || col < 0 || col >= colMax) return;
    float inv = 1.0f / cnt[row];
    float4 ev = *(const float4*)(emb + (size_t)col * DDIM + c);
    float* d = dst + (size_t)row * DOUTK + c;
    atomicAdd(d + 0, inv * ev.x);
    atomicAdd(d + 1, inv * ev.y);
    atomicAdd(d + 2, inv * ev.z);
    atomicAdd(d + 3, inv * ev.w);
}

// ---- tanh over one 100-wide column block of the N x 300 buffer ----
__global__ __launch_bounds__(256) void tanh_block(
    float* __restrict__ buf, int colBase, int total)
{
    int t = blockIdx.x * 256 + threadIdx.x;
    if (t >= total) return;
    int n = t / DDIM, d = t - n * DDIM;
    float* p = buf + (size_t)n * DOUTK + colBase + d;
    *p = tanhf(*p);
}

// ---- attention: exp(dot(rels, attn[l])) + per-row denominators, both layers ----
__global__ __launch_bounds__(256) void att_exp(
    const int* __restrict__ adj, const u16* __restrict__ rels, const float* __restrict__ attn,
    float* __restrict__ att0, float* __restrict__ att1,
    float* __restrict__ den0, float* __restrict__ den1, int nE)
{
    int w = blockIdx.x * 4 + (threadIdx.x >> 6);
    int lane = threadIdx.x & 63;
    if (w >= nE) return;
    const u16* r = rels + (size_t)w * DDIM;
    float r1 = bf2f(r[lane]);
    int d2 = lane + 64;
    float r2 = (d2 < DDIM) ? bf2f(r[d2]) : 0.f;
    float a0 = attn[lane];
    float a0b = (d2 < DDIM) ? attn[d2] : 0.f;
    float a1 = attn[DDIM + lane];
    float a1b = (d2 < DDIM) ? attn[DDIM + d2] : 0.f;
    float p0 = r1 * a0 + r2 * a0b;
    float p1 = r1 * a1 + r2 * a1b;
#pragma unroll
    for (int m = 32; m; m >>= 1) { p0 += __shfl_xor(p0, m, 64); p1 += __shfl_xor(p1, m, 64); }
    if (lane == 0) {
        float e0 = expf(p0), e1 = expf(p1);
        att0[w] = e0; att1[w] = e1;
        int row = adj[2 * w];
        if (row >= 0 && row < NN) {
            atomicAdd(&den0[row], e0);
            atomicAdd(&den1[row], e1);
        }
    }
}

__global__ __launch_bounds__(256) void att_norm(
    const int* __restrict__ adj, float* __restrict__ att0, float* __restrict__ att1,
    const float* __restrict__ den0, const float* __restrict__ den1, int nE)
{
    int t = blockIdx.x * 256 + threadIdx.x;
    if (t >= nE) return;
    int row = adj[2 * t];
    if (row < 0 || row >= NN) { att0[t] = 0.f; att1[t] = 0.f; return; }
    att0[t] /= den0[row];
    att1[t] /= den1[row];
}

// ---- one message-passing layer: dst[row] += att*(f[col] - 2*dot(f[col],rels)*rels) ----
__global__ __launch_bounds__(256) void edge_layer(
    const int* __restrict__ adj, const u16* __restrict__ rels, const float* __restrict__ att,
    const float* __restrict__ src, float* __restrict__ dst, int nE)
{
    int w = blockIdx.x * 4 + (threadIdx.x >> 6);
    int lane = threadIdx.x & 63;
    if (w >= nE) return;
    int row = adj[2 * w], col = adj[2 * w + 1];
    if (row < 0 || row >= NN || col < 0 || col >= NN) return;
    const u16* r = rels + (size_t)w * DDIM;
    const float* f = src + (size_t)col * DOUTK;
    float r1 = bf2f(r[lane]), f1 = f[lane];
    int d2 = lane + 64;
    float r2 = 0.f, f2 = 0.f;
    if (d2 < DDIM) { r2 = bf2f(r[d2]); f2 = f[d2]; }
    float p = f1 * r1 + f2 * r2;
#pragma unroll
    for (int m = 32; m; m >>= 1) p += __shfl_xor(p, m, 64);
    float a = att[w];
    float* o = dst + (size_t)row * DOUTK;
    atomicAdd(&o[lane], a * (f1 - 2.f * p * r1));
    if (d2 < DDIM) atomicAdd(&o[d2], a * (f2 - 2.f * p * r2));
}

// ---- inverse norms of proxy rows ----
__global__ __launch_bounds__(64) void proxy_norms(const float* __restrict__ proxy, float* __restrict__ pn)
{
    int k = threadIdx.x;
    if (k >= 64) return;
    float s = 0.f;
    for (int i = 0; i < DOUTK; ++i) { float v = proxy[k * DOUTK + i]; s += v * v; }
    pn[k] = 1.f / fmaxf(sqrtf(s), 1e-12f);
}

// ---- weight prepack kernels: fp32 -> frag-order bf16 [ktile][n][8] ----
// PT[kt<40][n<64][j] = proxy[n][kt*8+j]         (B for pa-GEMM: out @ proxy^T)
__global__ __launch_bounds__(256) void pack_proxyT(const float* __restrict__ p, u16* __restrict__ o)
{
    int t = blockIdx.x * 256 + threadIdx.x;
    if (t >= 40 * 64 * 8) return;
    int j = t & 7, n = (t >> 3) & 63, kt = t >> 9;
    int k = kt * 8 + j;
    o[t] = f2bf((k < 300) ? p[n * 300 + k] : 0.f);
}
// PB[kt<8][n<304][j] = proxy[kt*8+j][n]         (B for pf-GEMM: pa @ proxy)
__global__ __launch_bounds__(256) void pack_proxyB(const float* __restrict__ p, u16* __restrict__ o)
{
    int t = blockIdx.x * 256 + threadIdx.x;
    if (t >= 8 * 304 * 8) return;
    int j = t & 7, n = (t >> 3) % 304, kt = t / (304 * 8);
    int k = kt * 8 + j;
    o[t] = f2bf((k < 64 && n < 300) ? p[k * 300 + n] : 0.f);
}
// GB[kt<40][n<304][j] = gate[kt*8+j][n]         (B for gate-GEMM: pf @ gate)
__global__ __launch_bounds__(256) void pack_gateB(const float* __restrict__ p, u16* __restrict__ o)
{
    int t = blockIdx.x * 256 + threadIdx.x;
    if (t >= 40 * 304 * 8) return;
    int j = t & 7, n = (t >> 3) % 304, kt = t / (304 * 8);
    int k = kt * 8 + j;
    o[t] = f2bf((k < 300 && n < 300) ? p[k * 300 + n] : 0.f);
}

// ---- MFMA epilogue: 16 rows/block; A split hi/lo bf16, B single bf16 ----
// layouts (16x16x32 bf16): A[m=lane&15][k=quad*8+j]; C/D col=lane&15,row=quad*4+reg
__global__ __launch_bounds__(256) void epilogue_mfma(
    const float* __restrict__ outbuf, const u16* __restrict__ PT, const u16* __restrict__ PB,
    const u16* __restrict__ GB, const float* __restrict__ pn, const float* __restrict__ bias,
    float* __restrict__ dout, float alpha, int accumulate)
{
    __shared__ u32 s_o[16][324];   // out, packed hi/lo bf16 (k padded 300..319 = 0)
    __shared__ u32 s_f[16][324];   // pf,  packed hi/lo bf16
    __shared__ float s_pa[16][68];
    __shared__ float s_rn[16], s_pinv[16];

    const int tid = threadIdx.x;
    const int w = tid >> 6, quad = (tid >> 4) & 3, n15 = tid & 15;
    const size_t rowBase = (size_t)blockIdx.x * 16;

    for (int x = tid; x < 16 * 324; x += 256) {
        int r = x / 324, i = x - r * 324;
        float v = (i < 300) ? outbuf[(rowBase + r) * DOUTK + i] : 0.f;
        s_o[r][i] = pack_hl(v);
        if (i >= 300) s_f[r][i] = 0u;
    }
    __syncthreads();

    { // row inverse norms
        int r = tid >> 4, l = tid & 15;
        float s = 0.f;
        for (int i = l; i < 300; i += 16) { float v = unpack_f32(s_o[r][i]); s += v * v; }
#pragma unroll
        for (int m = 8; m; m >>= 1) s += __shfl_xor(s, m, 64);
        if (l == 0) s_rn[r] = 1.f / fmaxf(sqrtf(s), 1e-12f);
    }

    // ---- pa logits: D[16x64] = out @ proxy^T (each wave owns one 16-col tile) ----
    f32x4 accp = {0.f, 0.f, 0.f, 0.f};
    for (int kk = 0; kk < 10; ++kk) {
        short8 ah, al;
        unpack_frag(&s_o[n15][kk * 32 + quad * 8], ah, al);
        short8 b = *(const short8*)(PT + (((kk * 4 + quad) * 64) + (w * 16 + n15)) * 8);
        accp = __builtin_amdgcn_mfma_f32_16x16x32_bf16(ah, b, accp, 0, 0, 0);
        accp = __builtin_amdgcn_mfma_f32_16x16x32_bf16(al, b, accp, 0, 0, 0);
    }
    __syncthreads();   // s_rn ready
    {
        int col = w * 16 + n15;
        float pnc = pn[col];
#pragma unroll
        for (int g = 0; g < 4; ++g) {
            int row = quad * 4 + g;
            s_pa[row][col] = expf(accp[g] * s_rn[row] * pnc);
        }
    }
    __syncthreads();
    { // softmax denominators
        int r = tid >> 4, l = tid & 15;
        float s = s_pa[r][l] + s_pa[r][l + 16] + s_pa[r][l + 32] + s_pa[r][l + 48];
#pragma unroll
        for (int m = 8; m; m >>= 1) s += __shfl_xor(s, m, 64);
        if (l == 0) s_pinv[r] = 1.f / s;
    }
    __syncthreads();

    // ---- pf: T[16x304] = pa_raw @ proxy; pf = out - T * pinv[row] ----
    f32x4 accf[5];
#pragma unroll
    for (int t = 0; t < 5; ++t) accf[t] = (f32x4){0.f, 0.f, 0.f, 0.f};
    for (int kk = 0; kk < 2; ++kk) {
        short8 ah, al;
        {
            const float* src = &s_pa[n15][kk * 32 + quad * 8];
#pragma unroll
            for (int j = 0; j < 8; ++j) {
                float x = src[j];
                u32 h = __float_as_uint(x) >> 16;
                float hf = __uint_as_float(h << 16);
                ah[j] = (short)h;
                al[j] = (short)(__float_as_uint(x - hf) >> 16);
            }
        }
#pragma unroll
        for (int t = 0; t < 5; ++t) {
            int nt = w + 4 * t;
            if (nt < 19) {
                short8 b = *(const short8*)(PB + (((kk * 4 + quad) * 304) + (nt * 16 + n15)) * 8);
                accf[t] = __builtin_amdgcn_mfma_f32_16x16x32_bf16(ah, b, accf[t], 0, 0, 0);
                accf[t] = __builtin_amdgcn_mfma_f32_16x16x32_bf16(al, b, accf[t], 0, 0, 0);
            }
        }
    }
#pragma unroll
    for (int t = 0; t < 5; ++t) {
        int nt = w + 4 * t;
        if (nt < 19) {
            int col = nt * 16 + n15;
#pragma unroll
            for (int g = 0; g < 4; ++g) {
                int row = quad * 4 + g;
                float v = unpack_f32(s_o[row][col]) - accf[t][g] * s_pinv[row];
                s_f[row][col] = pack_hl(v);
            }
        }
    }
    __syncthreads();

    // ---- gate: Z[16x304] = pf @ gate_k ----
    f32x4 accg[5];
#pragma unroll
    for (int t = 0; t < 5; ++t) accg[t] = (f32x4){0.f, 0.f, 0.f, 0.f};
    for (int kk = 0; kk < 10; ++kk) {
        short8 ah, al;
        unpack_frag(&s_f[n15][kk * 32 + quad * 8], ah, al);
#pragma unroll
        for (int t = 0; t < 5; ++t) {
            int nt = w + 4 * t;
            if (nt < 19) {
                short8 b = *(const short8*)(GB + (((kk * 4 + quad) * 304) + (nt * 16 + n15)) * 8);
                accg[t] = __builtin_amdgcn_mfma_f32_16x16x32_bf16(ah, b, accg[t], 0, 0, 0);
                accg[t] = __builtin_amdgcn_mfma_f32_16x16x32_bf16(al, b, accg[t], 0, 0, 0);
            }
        }
    }
    // ---- gated mix + store ----
#pragma unroll
    for (int t = 0; t < 5; ++t) {
        int nt = w + 4 * t;
        if (nt < 19) {
            int col = nt * 16 + n15;
            if (col < 300) {
                float bb = bias[col];
#pragma unroll
                for (int g = 0; g < 4; ++g) {
                    int row = quad * 4 + g;
                    float z = accg[t][g] + bb;
                    float gg = 1.f / (1.f + expf(-z));
                    float ov = unpack_f32(s_o[row][col]);
                    float pv = unpack_f32(s_f[row][col]);
                    float res = (gg * ov + (1.f - gg) * pv) * alpha;
                    float* o = dout + (rowBase + row) * 600 + col;
                    if (accumulate) res += *o;
                    *o = res;
                }
            }
        }
    }
}

extern "C" void kernel_launch(void* const* d_in, const int* in_sizes, int n_in,
                              void* d_out, int out_size, void* d_ws, size_t ws_size,
                              hipStream_t stream)
{
    const int*   adj      = (const int*)d_in[0];
    const int*   r_index  = (const int*)d_in[1];
    const float* r_val    = (const float*)d_in[2];
    const int*   t_index  = (const int*)d_in[3];
    const int*   ent_adj  = (const int*)d_in[4];
    const int*   rel_adj  = (const int*)d_in[5];
    const int*   time_adj = (const int*)d_in[6];
    const float* ent_emb  = (const float*)d_in[7];
    const float* rel_emb  = (const float*)d_in[8];
    const float* time_emb = (const float*)d_in[9];
    const float* e_attn   = (const float*)d_in[10];
    const float* e_gate   = (const float*)d_in[11];
    const float* e_proxy  = (const float*)d_in[12];
    const float* e_bias   = (const float*)d_in[13];
    const float* r_attn   = (const float*)d_in[14];
    const float* r_gate   = (const float*)d_in[15];
    const float* r_proxy  = (const float*)d_in[16];
    const float* r_bias   = (const float*)d_in[17];
    float* out = (float*)d_out;

    char* ws = (char*)d_ws;
    size_t off = 0;
    auto alloc = [&](size_t bytes) { void* p = ws + off; off += (bytes + 255) & ~255ULL; return p; };
    u16* rels     = (u16*)alloc((size_t)EE * DDIM * 2);       // 80 MB
    float* outbuf = (float*)alloc((size_t)NN * DOUTK * 4);    // 120 MB (also rels fp32 scratch)
    float* att0   = (float*)alloc((size_t)EE * 4);
    float* att1   = (float*)alloc((size_t)EE * 4);
    float* den0   = (float*)alloc((size_t)NN * 4);
    float* den1   = (float*)alloc((size_t)NN * 4);
    float* cnt    = (float*)alloc((size_t)NN * 4);
    float* pnE    = (float*)alloc(64 * 4);
    float* pnR    = (float*)alloc(64 * 4);
    u16* PT_E     = (u16*)alloc(40 * 64 * 8 * 2);
    u16* PT_R     = (u16*)alloc(40 * 64 * 8 * 2);
    u16* PB_E     = (u16*)alloc(8 * 304 * 8 * 2);
    u16* PB_R     = (u16*)alloc(8 * 304 * 8 * 2);
    u16* GB_E     = (u16*)alloc(40 * 304 * 8 * 2);
    u16* GB_R     = (u16*)alloc(40 * 304 * 8 * 2);
    float* scratch = outbuf;  // time-shared: rels builds happen while outbuf is dead

    proxy_norms<<<1, 64, 0, stream>>>(e_proxy, pnE);
    proxy_norms<<<1, 64, 0, stream>>>(r_proxy, pnR);
    pack_proxyT<<<80, 256, 0, stream>>>(e_proxy, PT_E);
    pack_proxyT<<<80, 256, 0, stream>>>(r_proxy, PT_R);
    pack_proxyB<<<76, 256, 0, stream>>>(e_proxy, PB_E);
    pack_proxyB<<<76, 256, 0, stream>>>(r_proxy, PB_R);
    pack_gateB<<<380, 256, 0, stream>>>(e_gate, GB_E);
    pack_gateB<<<380, 256, 0, stream>>>(r_gate, GB_R);

    const int EHALF = EE / 2;
    const int sc_grid = (NNZK * 25 + 255) / 256;
    auto build_rels = [&](const int* sp, const float* emb, int kMax) {
        for (int h = 0; h < 2; ++h) {
            hipMemsetAsync(scratch, 0, (size_t)EHALF * DDIM * 4, stream);
            rels_scatter<<<sc_grid, 256, 0, stream>>>(sp, r_val, emb, scratch, h * EHALF, (h + 1) * EHALF, kMax, NNZK);
            rels_normalize<<<(EHALF + 3) / 4, 256, 0, stream>>>(scratch, rels, h * EHALF, EHALF);
        }
    };

    struct Enc {
        const int* fadj; const float* femb; int colMax; const float* attn;
        const u16* PT; const u16* PB; const u16* GB; const float* pn; const float* bias;
        int dcol; float alpha; int accum;
    };
    Enc encs[3] = {
        { ent_adj,  ent_emb,  NN,   e_attn, PT_E, PB_E, GB_E, pnE, e_bias,   0, 1.0f, 0 },
        { rel_adj,  rel_emb,  2000, r_attn, PT_R, PB_R, GB_R, pnR, r_bias, 300, 0.5f, 0 },
        { time_adj, time_emb, 1000, e_attn, PT_E, PB_E, GB_E, pnE, e_bias, 300, 0.5f, 1 },
    };

    const int fs_grid = (ADJK * 25 + 255) / 256;
    const int th_grid = (NN * DDIM + 255) / 256;
    const int ew_grid = (EE + 3) / 4;

    build_rels(r_index, rel_emb, 2000);     // relsR, used by enc 0 and 1
    for (int c = 0; c < 3; ++c) {
        if (c == 2) build_rels(t_index, time_emb, 1000);   // relsT replaces relsR (outbuf dead here)
        const Enc& e = encs[c];
        hipMemsetAsync(outbuf, 0, (size_t)NN * DOUTK * 4, stream);
        hipMemsetAsync(cnt, 0, (size_t)NN * 4, stream);
        count_kernel<<<(ADJK + 255) / 256, 256, 0, stream>>>(e.fadj, cnt, ADJK);
        feat_scatter<<<fs_grid, 256, 0, stream>>>(e.fadj, e.femb, cnt, outbuf, e.colMax, ADJK);
        tanh_block<<<th_grid, 256, 0, stream>>>(outbuf, 0, NN * DDIM);
        hipMemsetAsync(den0, 0, (size_t)NN * 4, stream);
        hipMemsetAsync(den1, 0, (size_t)NN * 4, stream);
        att_exp<<<ew_grid, 256, 0, stream>>>(adj, rels, e.attn, att0, att1, den0, den1, EE);
        att_norm<<<(EE + 255) / 256, 256, 0, stream>>>(adj, att0, att1, den0, den1, EE);
        edge_layer<<<ew_grid, 256, 0, stream>>>(adj, rels, att0, outbuf, outbuf + DDIM, EE);
        tanh_block<<<th_grid, 256, 0, stream>>>(outbuf, DDIM, NN * DDIM);
        edge_layer<<<ew_grid, 256, 0, stream>>>(adj, rels, att1, outbuf + DDIM, outbuf + 2 * DDIM, EE);
        tanh_block<<<th_grid, 256, 0, stream>>>(outbuf, 2 * DDIM, NN * DDIM);
        epilogue_mfma<<<NN / 16, 256, 0, stream>>>(outbuf, e.PT, e.PB, e.GB, e.pn, e.bias,
                                                   out + e.dcol, e.alpha, e.accum);
    }
}